// Round 8
// baseline (132.943 us; speedup 1.0000x reference)
//
#include <hip/hip_runtime.h>
#include <math.h>

// SEFusion: x [N=25, C=256, H=48, W=176] f32. V4 = CHW/4 = 540,672 float4.
#define CHW     2162688
#define V4      540672
#define NTOK    25
#define MAXCAV  5
#define NBATCH  8

// reduce geometry (R4-proven): per-token segments, compile-time trip count
#define BPT     64               // blocks per token
#define V4_BLK  8448             // V4 / BPT
#define ITERS   33               // V4_BLK / 256
#define RBLKS   (BPT * NTOK)     // 1600

// apply geometry: balanced flat chunks, 4 blocks/CU exactly
#define ABLKS   1024
#define CHUNK3  528              // V4 / ABLKS

typedef float f32x4 __attribute__((ext_vector_type(4)));

// =================== Kernel 1: reduce (R4 loop) + last-block gate =========
__global__ __launch_bounds__(256) void k_reduce_gate(
    const float4* __restrict__ x,
    const int*   __restrict__ record_len,
    const float* __restrict__ W1,
    const float* __restrict__ W2,
    const float* __restrict__ conv_w,
    float* __restrict__ psum,     // [NTOK*BPT]
    float* __restrict__ pmax,     // [NTOK*BPT]
    int*   __restrict__ counter,  // zeroed by memsetAsync each launch
    int*   __restrict__ starts,   // [NBATCH]
    float* __restrict__ coefs)    // [NBATCH*MAXCAV]
{
    const int tid  = threadIdx.x;
    const int t    = blockIdx.y;      // token
    const int blk  = blockIdx.x;      // 0..BPT-1
    const int lane = tid & 63;
    const int wave = tid >> 6;
    const long base = (long)t * V4 + (long)blk * V4_BLK;

    // ---- compile-time-bounded streaming loop (keeps 4 loads in flight) ---
    float s = 0.0f;
    float mx = -INFINITY;
    #pragma unroll 4
    for (int i = 0; i < ITERS; ++i) {
        float4 v = x[base + i * 256 + tid];
        s += (v.x + v.y) + (v.z + v.w);
        mx = fmaxf(mx, fmaxf(fmaxf(v.x, v.y), fmaxf(v.z, v.w)));
    }

    // ---- block tree reduction --------------------------------------------
    #pragma unroll
    for (int off = 32; off > 0; off >>= 1) {
        s += __shfl_xor(s, off, 64);
        mx = fmaxf(mx, __shfl_xor(mx, off, 64));
    }
    __shared__ float rs[4], rm[4];
    if (lane == 0) { rs[wave] = s; rm[wave] = mx; }
    __syncthreads();
    if (tid == 0) {
        psum[t * BPT + blk] = rs[0] + rs[1] + rs[2] + rs[3];
        pmax[t * BPT + blk] = fmaxf(fmaxf(rm[0], rm[1]), fmaxf(rm[2], rm[3]));
    }

    // ---- last arriving block runs the gate (pattern proven in R7) --------
    __shared__ int is_last;
    if (tid == 0) {
        __threadfence();                       // publish psum/pmax
        is_last = (atomicAdd(counter, 1) == RBLKS - 1);
    }
    __syncthreads();
    if (!is_last) return;
    __threadfence();                           // acquire all blocks' partials

    __shared__ float tsum[NTOK], tmax[NTOK];
    for (int tt = wave; tt < NTOK; tt += 4) {
        float ss = psum[tt * BPT + lane];
        float mm = pmax[tt * BPT + lane];
        #pragma unroll
        for (int off = 32; off > 0; off >>= 1) {
            ss += __shfl_xor(ss, off, 64);
            mm = fmaxf(mm, __shfl_xor(mm, off, 64));
        }
        if (lane == 0) { tsum[tt] = ss; tmax[tt] = mm; }
    }
    __syncthreads();

    if (tid < NBATCH) {
        const int b = tid;
        int start = 0;
        for (int i = 0; i < b; ++i) start += record_len[i];
        const int len = record_len[b];
        starts[b] = start;

        float xsq[2 * MAXCAV];
        #pragma unroll
        for (int m = 0; m < MAXCAV; ++m) {
            const bool valid = m < len;
            xsq[m]          = valid ? tsum[start + m] * (1.0f / (float)CHW) : 0.0f;
            xsq[MAXCAV + m] = valid ? tmax[start + m] : 0.0f;  // zero-pad: max=0
        }
        float h[MAXCAV];
        #pragma unroll
        for (int j = 0; j < MAXCAV; ++j) {
            float a = 0.0f;
            #pragma unroll
            for (int k = 0; k < 2 * MAXCAV; ++k) a += xsq[k] * W1[j * 2 * MAXCAV + k];
            h[j] = 1.0f / (1.0f + expf(-a));
        }
        #pragma unroll
        for (int m = 0; m < MAXCAV; ++m) {
            float g = 0.0f;
            #pragma unroll
            for (int j = 0; j < MAXCAV; ++j) g += h[j] * W2[m * MAXCAV + j];
            coefs[b * MAXCAV + m] = conv_w[m] * fmaxf(g, 0.0f);
        }
    }
}

// =================== Kernel 2: balanced apply (528 float4/block) ==========
__device__ __forceinline__ void relu_store(float ax, float ay, float az, float aw,
                                           float4* __restrict__ out, int o) {
    f32x4 acc;
    acc.x = fmaxf(ax, 0.0f);
    acc.y = fmaxf(ay, 0.0f);
    acc.z = fmaxf(az, 0.0f);
    acc.w = fmaxf(aw, 0.0f);
    __builtin_nontemporal_store(acc, (f32x4*)(out + o));
}

template <int LEN>
__device__ __forceinline__ void apply_idx(const float4* __restrict__ x,
                                          const float* c, float bias,
                                          int start, int obase, int idx,
                                          float4* __restrict__ out) {
    float ax = bias, ay = bias, az = bias, aw = bias;
    #pragma unroll
    for (int m = 0; m < LEN; ++m) {
        float4 v = x[(start + m) * V4 + idx];
        ax += c[m] * v.x;
        ay += c[m] * v.y;
        az += c[m] * v.z;
        aw += c[m] * v.w;
    }
    relu_store(ax, ay, az, aw, out, obase + idx);
}

template <int LEN>
__device__ __forceinline__ void apply_chunk(const float4* __restrict__ x,
                                            const float* c, float bias,
                                            int start, int obase, int base3,
                                            int tid, float4* __restrict__ out) {
    apply_idx<LEN>(x, c, bias, start, obase, base3 + tid, out);
    apply_idx<LEN>(x, c, bias, start, obase, base3 + 256 + tid, out);
    if (tid < CHUNK3 - 512)
        apply_idx<LEN>(x, c, bias, start, obase, base3 + 512 + tid, out);
}

__global__ __launch_bounds__(256) void k_apply(const float4* __restrict__ x,
                                               const int*   __restrict__ record_len,
                                               const int*   __restrict__ starts,
                                               const float* __restrict__ coefs,
                                               const float* __restrict__ conv_b,
                                               float4* __restrict__ out) {
    const int tid   = threadIdx.x;
    const int base3 = blockIdx.x * CHUNK3;
    const float bias = conv_b[0];

    for (int b = 0; b < NBATCH; ++b) {
        const int len   = record_len[b];
        const int start = starts[b];
        float c[MAXCAV];
        #pragma unroll
        for (int m = 0; m < MAXCAV; ++m) c[m] = coefs[b * MAXCAV + m];
        const int obase = b * V4;

        switch (len) {
            case 1:  apply_chunk<1>(x, c, bias, start, obase, base3, tid, out); break;
            case 2:  apply_chunk<2>(x, c, bias, start, obase, base3, tid, out); break;
            case 3:  apply_chunk<3>(x, c, bias, start, obase, base3, tid, out); break;
            case 4:  apply_chunk<4>(x, c, bias, start, obase, base3, tid, out); break;
            default: apply_chunk<5>(x, c, bias, start, obase, base3, tid, out); break;
        }
    }
}

extern "C" void kernel_launch(void* const* d_in, const int* in_sizes, int n_in,
                              void* d_out, int out_size, void* d_ws, size_t ws_size,
                              hipStream_t stream) {
    const float4* x  = (const float4*)d_in[0];
    const int*    rl = (const int*)d_in[1];
    const float*  W1 = (const float*)d_in[2];
    const float*  W2 = (const float*)d_in[3];
    const float*  cw = (const float*)d_in[4];
    const float*  cb = (const float*)d_in[5];
    float4* out = (float4*)d_out;

    char* ws = (char*)d_ws;
    int*   counter = (int*)  (ws);                   // 4 B (+60 pad)
    float* psum    = (float*)(ws + 64);              // 1600 floats
    float* pmax    = (float*)(ws + 64 + 6400);       // 1600 floats
    int*   starts  = (int*)  (ws + 64 + 12800);      // 8 ints (+ pad)
    float* coefs   = (float*)(ws + 64 + 12864);      // 40 floats

    hipMemsetAsync(counter, 0, sizeof(int), stream);
    k_reduce_gate<<<dim3(BPT, NTOK), 256, 0, stream>>>(x, rl, W1, W2, cw,
                                                       psum, pmax, counter,
                                                       starts, coefs);
    k_apply<<<ABLKS, 256, 0, stream>>>(x, rl, starts, coefs, cb, out);
}

// Round 9
// 88.085 us; speedup vs baseline: 1.5093x; 1.5093x over previous
//
#include <hip/hip_runtime.h>
#include <math.h>

// SEFusion: x [N=25, C=256, H=48, W=176] f32. V4 = CHW/4 = 540,672 float4.
#define CHW     2162688
#define V4      540672
#define NTOK    25
#define MAXCAV  5
#define NBATCH  8

// reduce geometry (R4-proven): per-token segments, compile-time trip count
#define BPT     64               // blocks per token
#define V4_BLK  8448             // V4 / BPT
#define ITERS   33               // V4_BLK / 256

// apply geometry: 2048 blocks = 8/CU exactly; V4 = 2048 * 264
#define ABLKS   2048
#define CHUNK3  264

typedef float f32x4 __attribute__((ext_vector_type(4)));

// =================== Kernel 1: per-token sum + max =========================
__global__ __launch_bounds__(256) void k_reduce(const float4* __restrict__ x,
                                                float* __restrict__ psum,
                                                float* __restrict__ pmax) {
    const int tid = threadIdx.x;
    const int t   = blockIdx.y;      // token
    const int blk = blockIdx.x;      // 0..BPT-1
    const long base = (long)t * V4 + (long)blk * V4_BLK;

    float s = 0.0f;
    float mx = -INFINITY;
    #pragma unroll 4
    for (int i = 0; i < ITERS; ++i) {
        float4 v = x[base + i * 256 + tid];
        s += (v.x + v.y) + (v.z + v.w);
        mx = fmaxf(mx, fmaxf(fmaxf(v.x, v.y), fmaxf(v.z, v.w)));
    }

    const int lane = tid & 63;
    const int wave = tid >> 6;
    #pragma unroll
    for (int off = 32; off > 0; off >>= 1) {
        s += __shfl_xor(s, off, 64);
        mx = fmaxf(mx, __shfl_xor(mx, off, 64));
    }
    __shared__ float rs[4], rm[4];
    if (lane == 0) { rs[wave] = s; rm[wave] = mx; }
    __syncthreads();
    if (tid == 0) {
        psum[t * BPT + blk] = rs[0] + rs[1] + rs[2] + rs[3];
        pmax[t * BPT + blk] = fmaxf(fmaxf(rm[0], rm[1]), fmaxf(rm[2], rm[3]));
    }
}

// =================== Kernel 2: finish reduction + gate MLP =================
__global__ __launch_bounds__(256) void k_gate(const float* __restrict__ psum,
                                              const float* __restrict__ pmax,
                                              const int*   __restrict__ record_len,
                                              const float* __restrict__ W1,
                                              const float* __restrict__ W2,
                                              const float* __restrict__ conv_w,
                                              int*   __restrict__ starts,
                                              float* __restrict__ coefs) {
    __shared__ float tsum[NTOK], tmax[NTOK];
    const int wave = threadIdx.x >> 6;
    const int lane = threadIdx.x & 63;

    for (int t = wave; t < NTOK; t += 4) {
        float s = psum[t * BPT + lane];
        float m = pmax[t * BPT + lane];
        #pragma unroll
        for (int off = 32; off > 0; off >>= 1) {
            s += __shfl_xor(s, off, 64);
            m = fmaxf(m, __shfl_xor(m, off, 64));
        }
        if (lane == 0) { tsum[t] = s; tmax[t] = m; }
    }
    __syncthreads();

    if ((int)threadIdx.x < NBATCH) {
        const int b = threadIdx.x;
        int start = 0;
        for (int i = 0; i < b; ++i) start += record_len[i];
        const int len = record_len[b];
        starts[b] = start;

        float xsq[2 * MAXCAV];
        #pragma unroll
        for (int m = 0; m < MAXCAV; ++m) {
            const bool valid = m < len;
            xsq[m]          = valid ? tsum[start + m] * (1.0f / (float)CHW) : 0.0f;
            xsq[MAXCAV + m] = valid ? tmax[start + m] : 0.0f;  // zero-pad: max=0
        }
        float h[MAXCAV];
        #pragma unroll
        for (int j = 0; j < MAXCAV; ++j) {
            float a = 0.0f;
            #pragma unroll
            for (int k = 0; k < 2 * MAXCAV; ++k) a += xsq[k] * W1[j * 2 * MAXCAV + k];
            h[j] = 1.0f / (1.0f + expf(-a));
        }
        #pragma unroll
        for (int m = 0; m < MAXCAV; ++m) {
            float g = 0.0f;
            #pragma unroll
            for (int j = 0; j < MAXCAV; ++j) g += h[j] * W2[m * MAXCAV + j];
            coefs[b * MAXCAV + m] = conv_w[m] * fmaxf(g, 0.0f);
        }
    }
}

// =================== Kernel 3: balanced apply (264 float4/block) ===========
__device__ __forceinline__ void relu_store(float ax, float ay, float az, float aw,
                                           float4* __restrict__ out, int o) {
    f32x4 acc;
    acc.x = fmaxf(ax, 0.0f);
    acc.y = fmaxf(ay, 0.0f);
    acc.z = fmaxf(az, 0.0f);
    acc.w = fmaxf(aw, 0.0f);
    __builtin_nontemporal_store(acc, (f32x4*)(out + o));
}

template <int LEN>
__device__ __forceinline__ void apply_idx(const float4* __restrict__ x,
                                          const float* c, float bias,
                                          int start, int obase, int idx,
                                          float4* __restrict__ out) {
    float ax = bias, ay = bias, az = bias, aw = bias;
    #pragma unroll
    for (int m = 0; m < LEN; ++m) {
        float4 v = x[(start + m) * V4 + idx];
        ax += c[m] * v.x;
        ay += c[m] * v.y;
        az += c[m] * v.z;
        aw += c[m] * v.w;
    }
    relu_store(ax, ay, az, aw, out, obase + idx);
}

template <int LEN>
__device__ __forceinline__ void apply_chunk(const float4* __restrict__ x,
                                            const float* c, float bias,
                                            int start, int obase, int base3,
                                            int tid, float4* __restrict__ out) {
    apply_idx<LEN>(x, c, bias, start, obase, base3 + tid, out);
    if (tid < CHUNK3 - 256)   // 8 threads handle the +256 remainder
        apply_idx<LEN>(x, c, bias, start, obase, base3 + 256 + tid, out);
}

__global__ __launch_bounds__(256) void k_apply(const float4* __restrict__ x,
                                               const int*   __restrict__ record_len,
                                               const int*   __restrict__ starts,
                                               const float* __restrict__ coefs,
                                               const float* __restrict__ conv_b,
                                               float4* __restrict__ out) {
    const int tid   = threadIdx.x;
    const int base3 = blockIdx.x * CHUNK3;
    const float bias = conv_b[0];

    for (int b = 0; b < NBATCH; ++b) {
        const int len   = record_len[b];
        const int start = starts[b];
        float c[MAXCAV];
        #pragma unroll
        for (int m = 0; m < MAXCAV; ++m) c[m] = coefs[b * MAXCAV + m];
        const int obase = b * V4;

        switch (len) {
            case 1:  apply_chunk<1>(x, c, bias, start, obase, base3, tid, out); break;
            case 2:  apply_chunk<2>(x, c, bias, start, obase, base3, tid, out); break;
            case 3:  apply_chunk<3>(x, c, bias, start, obase, base3, tid, out); break;
            case 4:  apply_chunk<4>(x, c, bias, start, obase, base3, tid, out); break;
            default: apply_chunk<5>(x, c, bias, start, obase, base3, tid, out); break;
        }
    }
}

extern "C" void kernel_launch(void* const* d_in, const int* in_sizes, int n_in,
                              void* d_out, int out_size, void* d_ws, size_t ws_size,
                              hipStream_t stream) {
    const float4* x  = (const float4*)d_in[0];
    const int*    rl = (const int*)d_in[1];
    const float*  W1 = (const float*)d_in[2];
    const float*  W2 = (const float*)d_in[3];
    const float*  cw = (const float*)d_in[4];
    const float*  cb = (const float*)d_in[5];
    float4* out = (float4*)d_out;

    char* ws = (char*)d_ws;
    float* psum   = (float*)(ws);              // 1600 floats
    float* pmax   = (float*)(ws + 6400);       // 1600 floats
    int*   starts = (int*)  (ws + 12800);      // 8 ints (+pad)
    float* coefs  = (float*)(ws + 12864);      // 40 floats

    k_reduce<<<dim3(BPT, NTOK), 256, 0, stream>>>(x, psum, pmax);
    k_gate<<<1, 256, 0, stream>>>(psum, pmax, rl, W1, W2, cw, starts, coefs);
    k_apply<<<ABLKS, 256, 0, stream>>>(x, rl, starts, coefs, cb, out);
}